// Round 5
// baseline (294.492 us; speedup 1.0000x reference)
//
#include <hip/hip_runtime.h>
#include <stdint.h>

#define PTS     256                // threads per block == points per chunk
#define DIM     10
#define FLOATS  (PTS * DIM)        // 2560 floats per chunk
#define VECS    (FLOATS / 4)       // 640 float4 per chunk
#define GRID    2048               // persistent blocks (~8/CU)

// clang vector type for nontemporal stores (__builtin_nontemporal_store
// rejects HIP's struct float4).
typedef float f32x4 __attribute__((ext_vector_type(4)));

// Codebook as compile-time constant; fully-unrolled uses constant-fold.
static constexpr float CB[32][10] = {
 {-1,-1,-1,-1,-1,-1,-1,-1,-1,-1},{-1,-1,-1,-1,1,1,-1,-1,-1,1},{-1,-1,-1,1,-1,-1,-1,-1,1,1},{-1,-1,-1,1,1,1,-1,-1,1,-1},
 {-1,-1,1,-1,-1,-1,-1,1,1,-1},{-1,-1,1,-1,1,1,-1,1,1,1},{-1,-1,1,1,-1,-1,-1,1,-1,1},{-1,-1,1,1,1,1,-1,1,-1,-1},
 {-1,1,-1,-1,-1,-1,1,1,-1,-1},{-1,1,-1,-1,1,1,1,1,-1,1},{-1,1,-1,1,-1,-1,1,1,1,1},{-1,1,-1,1,1,1,1,1,1,-1},
 {-1,1,1,-1,-1,-1,1,-1,1,-1},{-1,1,1,-1,1,1,1,-1,1,1},{-1,1,1,1,-1,-1,1,-1,-1,1},{-1,1,1,1,1,1,1,-1,-1,-1},
 {1,-1,-1,-1,-1,1,1,-1,-1,-1},{1,-1,-1,-1,1,-1,1,-1,-1,1},{1,-1,-1,1,-1,1,1,-1,1,1},{1,-1,-1,1,1,-1,1,-1,1,-1},
 {1,-1,1,-1,-1,1,1,1,1,-1},{1,-1,1,-1,1,-1,1,1,1,1},{1,-1,1,1,-1,1,1,1,-1,1},{1,-1,1,1,1,-1,1,1,-1,-1},
 {1,1,-1,-1,-1,1,-1,1,-1,-1},{1,1,-1,-1,1,-1,-1,1,-1,1},{1,1,-1,1,-1,1,-1,1,1,1},{1,1,-1,1,1,-1,-1,1,1,-1},
 {1,1,1,-1,-1,1,-1,-1,1,-1},{1,1,1,-1,1,-1,-1,-1,1,1},{1,1,1,1,-1,1,-1,-1,-1,1},{1,1,1,1,1,-1,-1,-1,-1,-1}};

// 10-bit sign mask per codeword (bit j set iff CB[k][j] == +1).
struct CBMasks { uint32_t m[32]; };
static constexpr CBMasks make_masks() {
    CBMasks r{};
    for (int k = 0; k < 32; ++k) {
        uint32_t mm = 0;
        for (int j = 0; j < DIM; ++j)
            if (CB[k][j] > 0.0f) mm |= (1u << j);
        r.m[k] = mm;
    }
    return r;
}
static constexpr CBMasks CBM = make_masks();

// Raw workgroup barrier WITHOUT the __syncthreads vmcnt(0) drain:
// LDS visibility (lgkmcnt(0)) + s_barrier, with compiler memory fences on
// both sides so C-level LDS/global ops can't be moved across. Global
// prefetch loads issued before this stay in flight across the barrier.
__device__ __forceinline__ void barrier_lds_only() {
    asm volatile("s_waitcnt lgkmcnt(0)" ::: "memory");
    __builtin_amdgcn_s_barrier();
    asm volatile("" ::: "memory");
}

__global__ __launch_bounds__(PTS) void softdec_kernel(
    const float* __restrict__ sig, float* __restrict__ out, int nc)
{
    // Double-buffered: writes to buffer b at iter t+2 are separated from the
    // last reads at iter t by two barriers.
    __shared__ float    sIn [2][FLOATS];   // 20 KiB
    __shared__ uint32_t sMask[2][PTS];     //  2 KiB

    const int tid = threadIdx.x;
    const int c0  = blockIdx.x * nc;       // first chunk of this block

    // ---- prologue: issue loads for chunk c0 ----
    float4 nxt0, nxt1, nxt2;
    {
        const float4* __restrict__ g = (const float4*)(sig + (size_t)c0 * FLOATS);
        nxt0 = g[tid];
        nxt1 = g[tid + PTS];
        nxt2 = g[(tid + 2 * PTS) < VECS ? (tid + 2 * PTS) : (VECS - 1)];
    }

    for (int t = 0; t < nc; ++t) {
        const int buf = t & 1;

        // ---- stage regs -> LDS (compiler inserts counted vmcnt wait here) ----
        float4* s4 = (float4*)sIn[buf];
        s4[tid]       = nxt0;
        s4[tid + PTS] = nxt1;
        if (tid < VECS - 2 * PTS) s4[tid + 2 * PTS] = nxt2;   // tid < 128

        // ---- issue prefetch for chunk t+1 (stays in flight across barriers) ----
        if (t + 1 < nc) {
            const float4* __restrict__ g =
                (const float4*)(sig + (size_t)(c0 + t + 1) * FLOATS);
            nxt0 = g[tid];
            nxt1 = g[tid + PTS];
            nxt2 = g[(tid + 2 * PTS) < VECS ? (tid + 2 * PTS) : (VECS - 1)];
        }

        barrier_lds_only();                 // staging visible; no vmcnt drain

        // ---- per-thread point; 32 signed sums + argmax. IDENTICAL summation
        // order and strict-'>' tie rule as all passing kernels. ----
        float x[DIM];
        #pragma unroll
        for (int j = 0; j < DIM; ++j) x[j] = sIn[buf][tid * DIM + j];

        float    best = -1e30f;
        uint32_t bm   = 0u;                              // codeword 0 (all -1)
        #pragma unroll
        for (int k = 0; k < 32; ++k) {
            float s = 0.0f;
            #pragma unroll
            for (int j = 0; j < DIM; ++j)
                s = (CB[k][j] > 0.0f) ? (s + x[j]) : (s - x[j]);
            if (s > best) { best = s; bm = CBM.m[k]; }
        }
        sMask[buf][tid] = bm;

        barrier_lds_only();                 // masks visible; no vmcnt drain

        // ---- epilogue: compose coalesced float4 from 1-2 point masks.
        // +1.0f=0x3F800000, -1.0f=0xBF800000 differ only in bit 31. ----
        f32x4* __restrict__ gout = (f32x4*)(out + (size_t)(c0 + t) * FLOATS);
        #pragma unroll
        for (int it = 0; it < 3; ++it) {
            const int i = tid + it * PTS;
            if (it < 2 || i < VECS) {
                const int gg = 4 * i;                  // first element of vec
                const int p0 = gg / DIM;               // magic-mul div by 10
                const int cc = gg - p0 * DIM;          // 0,2,4,6,8
                const uint32_t m0 = sMask[buf][p0];
                const uint32_t m1 = sMask[buf][(p0 + 1 < PTS) ? (p0 + 1) : p0];
                // bit j of mm = sign of element gg+j (m0 is 10-bit, so the
                // >>cc tail and <<(10-cc) head splice without overlap)
                const uint32_t mm = (m0 >> cc) | (m1 << (DIM - cc));
                f32x4 v;
                v.x = __uint_as_float(0xBF800000u ^ ((mm        & 1u) << 31));
                v.y = __uint_as_float(0xBF800000u ^ (((mm >> 1) & 1u) << 31));
                v.z = __uint_as_float(0xBF800000u ^ (((mm >> 2) & 1u) << 31));
                v.w = __uint_as_float(0xBF800000u ^ (((mm >> 3) & 1u) << 31));
                // write-once output: nontemporal keeps it from evicting the
                // L3-resident input (FETCH_SIZE was 84MB thanks to L3 hits)
                __builtin_nontemporal_store(v, gout + i);
            }
        }
    }
}

extern "C" void kernel_launch(void* const* d_in, const int* in_sizes, int n_in,
                              void* d_out, int out_size, void* d_ws, size_t ws_size,
                              hipStream_t stream) {
    const float* sig = (const float*)d_in[0];
    float* out = (float*)d_out;
    const int total  = in_sizes[0];        // B*N*D = 41,943,040 floats
    const int pts    = total / DIM;        // 4,194,304 points
    const int chunks = pts / PTS;          // 16,384 chunks (exact)
    int grid, nc;
    if (chunks % GRID == 0) { grid = GRID;   nc = chunks / GRID; }  // 2048 x 8
    else                    { grid = chunks; nc = 1; }              // fallback
    softdec_kernel<<<grid, PTS, 0, stream>>>(sig, out, nc);
}

// Round 6
// 284.086 us; speedup vs baseline: 1.0366x; 1.0366x over previous
//
#include <hip/hip_runtime.h>
#include <stdint.h>

#define DIM        10
#define WPTS       128                    // points per wave-chunk (2 per lane)
#define WFLOATS    (WPTS * DIM)           // 1280 floats per wave-chunk
#define WVECS      (WFLOATS / 4)          // 320 float4 per wave-chunk
#define WAVES      4                      // waves per block
#define THREADS    (WAVES * 64)           // 256
#define GRID       2048                   // 8192 independent waves

// Codebook as compile-time constant; fully-unrolled uses constant-fold.
static constexpr float CB[32][10] = {
 {-1,-1,-1,-1,-1,-1,-1,-1,-1,-1},{-1,-1,-1,-1,1,1,-1,-1,-1,1},{-1,-1,-1,1,-1,-1,-1,-1,1,1},{-1,-1,-1,1,1,1,-1,-1,1,-1},
 {-1,-1,1,-1,-1,-1,-1,1,1,-1},{-1,-1,1,-1,1,1,-1,1,1,1},{-1,-1,1,1,-1,-1,-1,1,-1,1},{-1,-1,1,1,1,1,-1,1,-1,-1},
 {-1,1,-1,-1,-1,-1,1,1,-1,-1},{-1,1,-1,-1,1,1,1,1,-1,1},{-1,1,-1,1,-1,-1,1,1,1,1},{-1,1,-1,1,1,1,1,1,1,-1},
 {-1,1,1,-1,-1,-1,1,-1,1,-1},{-1,1,1,-1,1,1,1,-1,1,1},{-1,1,1,1,-1,-1,1,-1,-1,1},{-1,1,1,1,1,1,1,-1,-1,-1},
 {1,-1,-1,-1,-1,1,1,-1,-1,-1},{1,-1,-1,-1,1,-1,1,-1,-1,1},{1,-1,-1,1,-1,1,1,-1,1,1},{1,-1,-1,1,1,-1,1,-1,1,-1},
 {1,-1,1,-1,-1,1,1,1,1,-1},{1,-1,1,-1,1,-1,1,1,1,1},{1,-1,1,1,-1,1,1,1,-1,1},{1,-1,1,1,1,-1,1,1,-1,-1},
 {1,1,-1,-1,-1,1,-1,1,-1,-1},{1,1,-1,-1,1,-1,-1,1,-1,1},{1,1,-1,1,-1,1,-1,1,1,1},{1,1,-1,1,1,-1,-1,1,1,-1},
 {1,1,1,-1,-1,1,-1,-1,1,-1},{1,1,1,-1,1,-1,-1,-1,1,1},{1,1,1,1,-1,1,-1,-1,-1,1},{1,1,1,1,1,-1,-1,-1,-1,-1}};

// 10-bit sign mask per codeword (bit j set iff CB[k][j] == +1).
struct CBMasks { uint32_t m[32]; };
static constexpr CBMasks make_masks() {
    CBMasks r{};
    for (int k = 0; k < 32; ++k) {
        uint32_t mm = 0;
        for (int j = 0; j < DIM; ++j)
            if (CB[k][j] > 0.0f) mm |= (1u << j);
        r.m[k] = mm;
    }
    return r;
}
static constexpr CBMasks CBM = make_masks();

// Per-point signed-correlation argmax. IDENTICAL summation order and
// strict-'>' tie rule as all passing kernels (bit-identical output).
__device__ __forceinline__ uint32_t argmax_mask(const float* __restrict__ x) {
    float    best = -1e30f;
    uint32_t bm   = 0u;                               // codeword 0 (all -1)
    #pragma unroll
    for (int k = 0; k < 32; ++k) {
        float s = 0.0f;
        #pragma unroll
        for (int j = 0; j < DIM; ++j)
            s = (CB[k][j] > 0.0f) ? (s + x[j]) : (s - x[j]);   // add/sub chain
        if (s > best) { best = s; bm = CBM.m[k]; }             // cmp + cndmask
    }
    return bm;
}

// ZERO inter-wave coupling: no s_barrier / __syncthreads anywhere.
// - input exchange: wave-PRIVATE LDS slice (DS ops from one wave execute in
//   program order -> own-wave write-then-read needs only lgkmcnt, which the
//   compiler inserts; no barrier).
// - mask exchange: ds_bpermute (in-register cross-lane, no barrier).
// Waves grid-stride independently with a 1-deep load pipeline.
__global__ __launch_bounds__(THREADS) void softdec_kernel(
    const float* __restrict__ sig, float* __restrict__ out, int totw)
{
    __shared__ float sIn[WAVES][WFLOATS];       // 20 KiB, one 5-KiB slice/wave

    const int lane = threadIdx.x & 63;
    const int wv   = threadIdx.x >> 6;
    const int nw   = GRID * WAVES;              // 8192 waves
    float* __restrict__ sW = sIn[wv];

    const float4* __restrict__ gin = (const float4*)sig;

    int w = blockIdx.x * WAVES + wv;            // this wave's first chunk

    // ---- prologue: issue chunk-w loads (coalesced dwordx4) ----
    float4 p0, p1, p2, p3, p4;
    {
        const float4* __restrict__ g = gin + (size_t)w * WVECS;
        p0 = g[lane];       p1 = g[lane + 64];  p2 = g[lane + 128];
        p3 = g[lane + 192]; p4 = g[lane + 256];
    }

    while (w < totw) {
        // ---- stage to wave-private LDS (compiler waits vmcnt here) ----
        float4* __restrict__ s4 = (float4*)sW;
        s4[lane]       = p0;  s4[lane +  64] = p1;  s4[lane + 128] = p2;
        s4[lane + 192] = p3;  s4[lane + 256] = p4;

        // ---- issue next chunk's loads; they fly during compute ----
        const int wn = w + nw;
        if (wn < totw) {
            const float4* __restrict__ g = gin + (size_t)wn * WVECS;
            p0 = g[lane];       p1 = g[lane + 64];  p2 = g[lane + 128];
            p3 = g[lane + 192]; p4 = g[lane + 256];
        }

        // ---- read MY two points: 80 B contiguous = 5x ds_read_b128.
        // (stride 80 B tiles all 32 banks uniformly: conflict-optimal) ----
        const float4* __restrict__ sp = (const float4*)(sW + lane * 2 * DIM);
        const float4 a0 = sp[0], a1 = sp[1], a2 = sp[2], a3 = sp[3], a4 = sp[4];
        float xA[DIM], xB[DIM];
        xA[0]=a0.x; xA[1]=a0.y; xA[2]=a0.z; xA[3]=a0.w;
        xA[4]=a1.x; xA[5]=a1.y; xA[6]=a1.z; xA[7]=a1.w;
        xA[8]=a2.x; xA[9]=a2.y;
        xB[0]=a2.z; xB[1]=a2.w;
        xB[2]=a3.x; xB[3]=a3.y; xB[4]=a3.z; xB[5]=a3.w;
        xB[6]=a4.x; xB[7]=a4.y; xB[8]=a4.z; xB[9]=a4.w;

        // ---- argmax both points; pack masks (pt 2*lane, 2*lane+1) ----
        const uint32_t pk = argmax_mask(xA) | (argmax_mask(xB) << DIM);

        // ---- epilogue: coalesced dwordx4 stores; masks via bpermute ----
        float4* __restrict__ gout = (float4*)out + (size_t)w * WVECS;
        #pragma unroll
        for (int q = 0; q < 5; ++q) {
            const int v  = q * 64 + lane;        // vec index in chunk [0,320)
            const int gg = 4 * v;                // first element of vec
            const int pA = gg / DIM;             // point 0..127 (magic-mul)
            const int cc = gg - pA * DIM;        // 0,2,4,6,8
            const int pB = (pA + 1 < WPTS) ? (pA + 1) : (WPTS - 1);
            // packed masks live in lane p>>1 of THIS wave
            const uint32_t pkA = (uint32_t)__builtin_amdgcn_ds_bpermute(
                                     (pA >> 1) << 2, (int)pk);
            const uint32_t pkB = (uint32_t)__builtin_amdgcn_ds_bpermute(
                                     (pB >> 1) << 2, (int)pk);
            const uint32_t A = (pkA >> ((pA & 1) * DIM)) & 0x3FFu;
            const uint32_t B = (pkB >> ((pB & 1) * DIM)) & 0x3FFu;
            // bit j of mm = sign of element gg+j (splice: tail of A, head of B)
            const uint32_t mm = (A >> cc) | (B << (DIM - cc));
            float4 o;
            o.x = __uint_as_float(0xBF800000u ^ ((mm        & 1u) << 31));
            o.y = __uint_as_float(0xBF800000u ^ (((mm >> 1) & 1u) << 31));
            o.z = __uint_as_float(0xBF800000u ^ (((mm >> 2) & 1u) << 31));
            o.w = __uint_as_float(0xBF800000u ^ (((mm >> 3) & 1u) << 31));
            gout[v] = o;                          // global_store_dwordx4
        }
        w = wn;
    }
}

extern "C" void kernel_launch(void* const* d_in, const int* in_sizes, int n_in,
                              void* d_out, int out_size, void* d_ws, size_t ws_size,
                              hipStream_t stream) {
    const float* sig = (const float*)d_in[0];
    float* out = (float*)d_out;
    const int total = in_sizes[0];            // B*N*D = 41,943,040 floats
    const int pts   = total / DIM;            // 4,194,304 points
    const int totw  = pts / WPTS;             // 32,768 wave-chunks (exact)
    softdec_kernel<<<GRID, THREADS, 0, stream>>>(sig, out, totw);
}